// Round 5
// baseline (125.124 us; speedup 1.0000x reference)
//
#include <hip/hip_runtime.h>
#include <hip/hip_bf16.h>

#define N_NODES 8192
#define DIM 128
#define MASK_THRESH 0.8f
#define RB 512            // row-blocks: 8192 / 16 rows
#define KSTEP 128         // k elements staged per step

using f32x4  = __attribute__((ext_vector_type(4))) float;
using bf16x8 = __attribute__((ext_vector_type(8))) short;

static __device__ __forceinline__ short f2bf(float f) {
    unsigned u = __builtin_bit_cast(unsigned, f);
    u += 0x7fffu + ((u >> 16) & 1u);
    return (short)(u >> 16);
}

// async global->LDS, 16B/lane; LDS dest = wave-uniform base + lane*16 (linear)
static __device__ __forceinline__ void gload16(const void* gsrc, void* ldst) {
    __builtin_amdgcn_global_load_lds(
        (const __attribute__((address_space(1))) unsigned int*)gsrc,
        (__attribute__((address_space(3))) unsigned int*)ldst,
        16, 0, 0);
}

// ---------------------------------------------------------------------------
// Kernel 1: V = X@W^T + b stored FRAGMENT-MAJOR as bf16:
//   Vf[((kb*8 + t)*64 + lane)*8 + e] = V[j][d]
//   where j = kb*32 + ((lane>>4)&3)*8 + e  (mfma K index),
//         d = t*16 + (lane&15)             (mfma N index).
// A wave's B-fragment for (kb, t) is then ONE contiguous 1KB load.
// ---------------------------------------------------------------------------
__global__ __launch_bounds__(256) void build_vf_kernel(
    const float* __restrict__ X, const float* __restrict__ W,
    const float* __restrict__ bias, short* __restrict__ Vf) {
    __shared__ float xs[32][128];
    const int jt = blockIdx.x * 32;
    for (int e = threadIdx.x; e < 32 * 128; e += 256) {
        xs[e >> 7][e & 127] = X[(size_t)(jt + (e >> 7)) * DIM + (e & 127)];
    }
    __syncthreads();
    const int d  = threadIdx.x & 127;
    const int jh = threadIdx.x >> 7;     // which 16-node half
    float bv = bias[d];
    float acc[16];
#pragma unroll
    for (int i = 0; i < 16; i++) acc[i] = bv;
    const float* wrow = W + (size_t)d * DIM;
    for (int k = 0; k < DIM; k += 4) {
        f32x4 wv = *(const f32x4*)(wrow + k);
#pragma unroll
        for (int i = 0; i < 16; i++) {
            f32x4 xv = *(const f32x4*)(&xs[jh * 16 + i][k]);
            acc[i] = fmaf(xv[0], wv[0], acc[i]);
            acc[i] = fmaf(xv[1], wv[1], acc[i]);
            acc[i] = fmaf(xv[2], wv[2], acc[i]);
            acc[i] = fmaf(xv[3], wv[3], acc[i]);
        }
    }
    bf16x8 o0, o1;
#pragma unroll
    for (int i = 0; i < 8; i++) { o0[i] = f2bf(acc[i]); o1[i] = f2bf(acc[8 + i]); }
    // j = jt + jh*16 + i : i<8 -> kg = 2*jh, i>=8 -> kg = 2*jh+1
    const int kb = jt >> 5;
    const int t  = d >> 4;
    short* base = Vf + ((size_t)(kb * 8 + t) * 64 + (d & 15) + 32 * jh) * 8;
    *(bf16x8*)(base)       = o0;   // kg = 2*jh
    *(bf16x8*)(base + 128) = o1;   // kg = 2*jh+1  (+16 lanes * 8 shorts)
}

// ---------------------------------------------------------------------------
// Kernel 2: fused masked-softmax(A) @ V.
//   Block: 256 thr (4 waves) = 16 rows x kchunk; wave w owns k-sub [w*32,+32)
//   of each KSTEP=128 step. A staged in LDS (8KB, double-buffered, XOR-swizzled
//   source + swizzled ds_read_b128). B-fragments read DIRECTLY from L2-resident
//   Vf (1KB contiguous per load, no LDS). Pipeline: stage(t+1); compute(t);
//   one barrier per step.
// ---------------------------------------------------------------------------
template <int WRITE_PARTIAL>
__global__ __launch_bounds__(256, 4) void fused_kernel(
    const float* __restrict__ A, const short* __restrict__ Vf,
    float* __restrict__ dst, float* __restrict__ Zp, int kchunk) {

    __shared__ __align__(16) float smem[8448];   // 2 x 8KB A-buf; reused as accs[4][16][132]
    __shared__ float zs[4][16];

    const int tid   = threadIdx.x;
    const int w     = tid >> 6;          // wave = k-sub slice
    const int lane  = tid & 63;
    const int row_a = lane & 15;
    const int kg    = lane >> 4;
    const int rb    = blockIdx.x & (RB - 1);
    const int chunk = blockIdx.x >> 9;
    const int r0    = rb * 16;
    const int k0    = chunk * kchunk;
    const int nsteps = kchunk >> 7;

    // --- staging addresses: 2 instrs/wave, each 2 rows x 512B ---
    const float* asrc[2]; int adst_off[2];
#pragma unroll
    for (int i = 0; i < 2; i++) {
        const int arow = w * 4 + i * 2 + (lane >> 5);
        asrc[i] = A + (size_t)(r0 + arow) * N_NODES + k0 + (((lane & 31) ^ (arow & 7)) << 2);
        adst_off[i] = (w * 4 + i * 2) * 128;     // wave-uniform base; +lane*16B implicit
    }
    // --- A-fragment read offsets (swizzled) ---
    const int aoff0 = row_a * 128 + (((w * 8 + kg * 2 + 0) ^ (row_a & 7)) << 2);
    const int aoff1 = row_a * 128 + (((w * 8 + kg * 2 + 1) ^ (row_a & 7)) << 2);
    // --- Vf fragment pointer: kb = k0/32 + ks*4 + w ---
    const short* vfp = Vf + ((size_t)((k0 >> 5) + w) * 8 * 64 + lane) * 8;

    f32x4 acc[8];
#pragma unroll
    for (int t = 0; t < 8; t++) acc[t] = (f32x4)0.0f;
    float zacc = 0.0f;

    // prologue: stage step 0 into buf 0
#pragma unroll
    for (int i = 0; i < 2; i++) gload16(asrc[i], smem + adst_off[i]);

    for (int ks = 0; ks < nsteps; ks++) {
        __syncthreads();   // stage(ks) complete+visible; prior reads of other buf done
        if (ks + 1 < nsteps) {
            float* nbuf = smem + ((ks + 1) & 1) * 2048;
#pragma unroll
            for (int i = 0; i < 2; i++)
                gload16(asrc[i] + (size_t)(ks + 1) * KSTEP, nbuf + adst_off[i]);
        }
        const float* ab = smem + (ks & 1) * 2048;
        const f32x4 av0 = *(const f32x4*)(ab + aoff0);
        const f32x4 av1 = *(const f32x4*)(ab + aoff1);
        float p[8];
#pragma unroll
        for (int i = 0; i < 4; i++) {
            p[i]     = (av0[i] > MASK_THRESH) ? __expf(av0[i]) : 0.0f;
            p[i + 4] = (av1[i] > MASK_THRESH) ? __expf(av1[i]) : 0.0f;
        }
        bf16x8 af;
#pragma unroll
        for (int i = 0; i < 8; i++) { zacc += p[i]; af[i] = f2bf(p[i]); }
        const short* vstep = vfp + (size_t)ks * 16384;   // +4 kb * 8 t * 512
#pragma unroll
        for (int t = 0; t < 8; t++) {
            const bf16x8 bv = *(const bf16x8*)(vstep + t * 512);
            acc[t] = __builtin_amdgcn_mfma_f32_16x16x32_bf16(af, bv, acc[t], 0, 0, 0);
        }
    }

    // --- Z: fold 4 k-groups; lanes 0..15 hold row sums for this wave ---
    zacc += __shfl_xor(zacc, 16);
    zacc += __shfl_xor(zacc, 32);
    if (lane < 16) zs[w][lane] = zacc;

    __syncthreads();                     // staging/reads done; smem reusable
    float* accs = smem;                  // [4][16][132]
#pragma unroll
    for (int t = 0; t < 8; t++)
#pragma unroll
        for (int r = 0; r < 4; r++)
            accs[(w * 16 + kg * 4 + r) * 132 + t * 16 + row_a] = acc[t][r];
    __syncthreads();

    // final: 256 threads, each row=tid>>4, cols (tid&15)*8 .. +7
    {
        const int row = tid >> 4;
        const int c8  = (tid & 15) * 8;
        float zt = zs[0][row] + zs[1][row] + zs[2][row] + zs[3][row];
        f32x4 s0 = (f32x4)0.0f, s1 = (f32x4)0.0f;
#pragma unroll
        for (int ww = 0; ww < 4; ww++) {
            const float* pp = &accs[(ww * 16 + row) * 132 + c8];
            s0 += *(const f32x4*)(pp);
            s1 += *(const f32x4*)(pp + 4);
        }
        if (WRITE_PARTIAL) {
            float* nd = dst + ((size_t)chunk * N_NODES + r0 + row) * DIM + c8;
            *(f32x4*)(nd)     = s0;
            *(f32x4*)(nd + 4) = s1;
            if (tid < 16) Zp[(size_t)chunk * N_NODES + r0 + tid] =
                zs[0][tid] + zs[1][tid] + zs[2][tid] + zs[3][tid];
        } else {
            f32x4 o0, o1;
#pragma unroll
            for (int j = 0; j < 4; j++) {
                float v0 = s0[j] / zt, v1 = s1[j] / zt;
                o0[j] = (v0 > 0.0f) ? v0 : 0.01f * v0;
                o1[j] = (v1 > 0.0f) ? v1 : 0.01f * v1;
            }
            float* od = dst + (size_t)(r0 + row) * DIM + c8;
            *(f32x4*)(od)     = o0;
            *(f32x4*)(od + 4) = o1;
        }
    }
}

// ---------------------------------------------------------------------------
// Kernel 3: sum S partials, normalize, leaky_relu. float4 per thread.
// ---------------------------------------------------------------------------
__global__ __launch_bounds__(256) void reduce_kernel(
    const float* __restrict__ num, const float* __restrict__ Zp,
    float* __restrict__ out, int S) {
    const size_t i4 = (size_t)blockIdx.x * 256 + threadIdx.x;  // quad index
    const int r  = (int)(i4 >> 5);
    const int c4 = (int)(i4 & 31) * 4;
    f32x4 s = (f32x4)0.0f;
    float z = 0.0f;
    for (int p = 0; p < S; p++) {
        s += *(const f32x4*)(num + ((size_t)p * N_NODES + r) * DIM + c4);
        z += Zp[(size_t)p * N_NODES + r];
    }
    f32x4 o;
#pragma unroll
    for (int j = 0; j < 4; j++) {
        const float v = s[j] / z;
        o[j] = (v > 0.0f) ? v : 0.01f * v;
    }
    *(f32x4*)(out + (size_t)r * DIM + c4) = o;
}

extern "C" void kernel_launch(void* const* d_in, const int* in_sizes, int n_in,
                              void* d_out, int out_size, void* d_ws, size_t ws_size,
                              hipStream_t stream) {
    const float* A = (const float*)d_in[0];
    const float* X = (const float*)d_in[1];
    const float* W = (const float*)d_in[2];
    const float* b = (const float*)d_in[3];
    float* out = (float*)d_out;

    const size_t VF_BYTES = (size_t)DIM * N_NODES * 2;   // 2 MiB
    short* Vf = (short*)d_ws;
    build_vf_kernel<<<N_NODES / 32, 256, 0, stream>>>(X, W, b, Vf);

    const size_t per_split = ((size_t)N_NODES * DIM + N_NODES) * sizeof(float);
    int S = 1;
    for (int cand = 4; cand >= 1; cand >>= 1) {
        if (VF_BYTES + (size_t)cand * per_split <= ws_size) { S = cand; break; }
    }

    if (S >= 2) {
        float* num = (float*)((char*)d_ws + VF_BYTES);
        float* Zp  = num + (size_t)S * N_NODES * DIM;
        fused_kernel<1><<<RB * S, 256, 0, stream>>>(A, Vf, num, Zp, N_NODES / S);
        reduce_kernel<<<(N_NODES * DIM / 4) / 256, 256, 0, stream>>>(num, Zp, out, S);
    } else {
        fused_kernel<0><<<RB, 256, 0, stream>>>(A, Vf, out, nullptr, N_NODES);
    }
}